// Round 2
// 1635.463 us; speedup vs baseline: 1.0353x; 1.0353x over previous
//
#include <hip/hip_runtime.h>
#include <hip/hip_fp16.h>
#include <math.h>

#define TWO_PI_F 6.2831853071795864769f

constexpr int T     = 256;
constexpr int BATCH = 32;
constexpr int NIN   = 28;
constexpr int NH    = 1024;
constexpr int NOUT  = 10;

constexpr int NBLK = 64;     // 16 row-groups x 4 batch-groups
constexpr int NTHR = 512;    // 8 waves: wave w -> (row-tile = w&3, khalf = w>>2)
constexpr int BROWS = 64;    // rows per block
constexpr int BB    = 8;     // batches per block

typedef unsigned int   uint;
typedef unsigned short ushort;
typedef unsigned long long ull;
typedef _Float16 half8 __attribute__((ext_vector_type(8)));
typedef float    f32x4 __attribute__((ext_vector_type(4)));

// ---- ws byte offsets ----
constexpr size_t OFF_W16 = 0;                                    // ushort [1024][1024] fp16 W = 2 MB
constexpr size_t OFF_INP = 2ull * 1024 * 1024;                   // float [T][BATCH][NH] = 32 MB
constexpr size_t OFF_SCT = OFF_INP + (size_t)T * NH * BATCH * 4; // ushort [2][4][16][1024] = 256 KB
constexpr size_t OFF_STF = OFF_SCT + 2ull * 4 * 16 * 1024 * 2;   // float [BATCH][NH] = 128 KB
constexpr size_t OFF_FLG = OFF_STF + (size_t)BATCH * NH * 4;     // flags, 8 KB

__device__ __forceinline__ void st32(uint* p, uint v) {
  __hip_atomic_store(p, v, __ATOMIC_RELAXED, __HIP_MEMORY_SCOPE_AGENT);
}

// Batched device-scope (sc1) B-fragment load: 16 x dwordx4 at 64B stride from
// one base, ONE waitcnt (R6-proven).
__device__ __forceinline__ void ldB(const ushort* base, uint4 bf[16]) {
  asm volatile(
    "global_load_dwordx4 %0, %16, off sc1\n\t"
    "global_load_dwordx4 %1, %16, off offset:64 sc1\n\t"
    "global_load_dwordx4 %2, %16, off offset:128 sc1\n\t"
    "global_load_dwordx4 %3, %16, off offset:192 sc1\n\t"
    "global_load_dwordx4 %4, %16, off offset:256 sc1\n\t"
    "global_load_dwordx4 %5, %16, off offset:320 sc1\n\t"
    "global_load_dwordx4 %6, %16, off offset:384 sc1\n\t"
    "global_load_dwordx4 %7, %16, off offset:448 sc1\n\t"
    "global_load_dwordx4 %8, %16, off offset:512 sc1\n\t"
    "global_load_dwordx4 %9, %16, off offset:576 sc1\n\t"
    "global_load_dwordx4 %10, %16, off offset:640 sc1\n\t"
    "global_load_dwordx4 %11, %16, off offset:704 sc1\n\t"
    "global_load_dwordx4 %12, %16, off offset:768 sc1\n\t"
    "global_load_dwordx4 %13, %16, off offset:832 sc1\n\t"
    "global_load_dwordx4 %14, %16, off offset:896 sc1\n\t"
    "global_load_dwordx4 %15, %16, off offset:960 sc1\n\t"
    "s_waitcnt vmcnt(0)"
    : "=&v"(bf[0]), "=&v"(bf[1]), "=&v"(bf[2]), "=&v"(bf[3]),
      "=&v"(bf[4]), "=&v"(bf[5]), "=&v"(bf[6]), "=&v"(bf[7]),
      "=&v"(bf[8]), "=&v"(bf[9]), "=&v"(bf[10]), "=&v"(bf[11]),
      "=&v"(bf[12]), "=&v"(bf[13]), "=&v"(bf[14]), "=&v"(bf[15])
    : "v"(base)
    : "memory");
}

// Per-batch-group barrier (16 blocks). The 4 bg chains are fully independent:
// block (rg,bg) consumes only scT[p][bg][*][*], produced by the 16 blocks that
// share bg. Flags laid out flags[(bg*16+rg)*32] (128B apart). RELEASE on the
// flag store is REQUIRED (R7: sc1-store + vmcnt-drain + relaxed flag is not a
// publish; the release's cache maintenance provides the ordering).
__device__ __forceinline__ void gbar(unsigned* flags, unsigned step, int tid,
                                     int rg, int bg) {
  __syncthreads();
  if (tid == 0)
    __hip_atomic_store(&flags[(bg * 16 + rg) * 32], step, __ATOMIC_RELEASE,
                       __HIP_MEMORY_SCOPE_AGENT);
  if (tid < 16)
    while (__hip_atomic_load(&flags[(bg * 16 + tid) * 32], __ATOMIC_RELAXED,
                             __HIP_MEMORY_SCOPE_AGENT) < step)
      __builtin_amdgcn_s_sleep(1);
  __syncthreads();
}

// ---- prep: W -> fp16 ----
__global__ __launch_bounds__(256) void prep_w16(const float* __restrict__ Wh,
                                                ushort* __restrict__ w16) {
  const int m = blockIdx.x * 256 + threadIdx.x;
  w16[m] = __builtin_bit_cast(ushort, (_Float16)Wh[m]);
}

// ---- prep: inp[t][b][i] = Wi_w[i,:]·x[t,b,:] + Wi_b[i] + omega[i] ----
__global__ __launch_bounds__(256) void prep_inp(const float* __restrict__ x,
                                                const float* __restrict__ Wi_w,
                                                const float* __restrict__ Wi_b,
                                                const float* __restrict__ omega,
                                                float* __restrict__ inp) {
  const int t = blockIdx.x;
  const int b = blockIdx.y;
  const float* xr = x + ((size_t)t * BATCH + b) * NIN;
#pragma unroll
  for (int u = 0; u < 4; ++u) {
    const int i = u * 256 + threadIdx.x;
    const float* wr = Wi_w + (size_t)i * NIN;
    float acc = Wi_b[i] + omega[i];
#pragma unroll
    for (int k = 0; k < NIN; ++k) acc += xr[k] * wr[k];
    inp[((size_t)t * BATCH + b) * NH + i] = acc;
  }
}

// ---- the scan: block = (row-group, batch-group); 4 independent bg-chains ----
__global__ __launch_bounds__(NTHR, 2) void kuramoto_scan(
    const float*  __restrict__ inp,   // [T][BATCH][NH]
    const ushort* __restrict__ w16,   // [1024][1024] fp16
    ushort*       __restrict__ scT,   // [2][4 bg][16 n][1024 i]; n: 0-7 sin, 8-15 cos
    float*        __restrict__ stF,   // [BATCH][NH]
    unsigned*     __restrict__ flags)
{
  // D-partials: pd[kh][rt][n][row16 (+4 pad)]
  __shared__ float pd[2 * 4 * 16 * 20];   // 10 KB

  const int tid  = threadIdx.x;
  const int bid  = blockIdx.x;
  const int rg   = bid >> 2;       // row-group: rows rg*64 .. +63
  const int bg   = bid & 3;        // batch-group: batches bg*8 .. +7
  const int lane = tid & 63;
  const int w    = tid >> 6;
  const int rt   = w & 3;          // row-tile within block (16 rows)
  const int kh   = w >> 2;         // K-half
  const int m    = lane & 15;      // A: M index / B,D: N index
  const int quad = lane >> 4;

  // ---- A-fragments (W rows) once into registers: 16 frags x 4 VGPR ----
  half8 af[16];
  {
    const ushort* wbase = w16 + (size_t)(rg * 64 + rt * 16 + m) * NH + kh * 512 + quad * 8;
#pragma unroll
    for (int ks = 0; ks < 16; ++ks)
      af[ks] = __builtin_bit_cast(half8, *(const uint4*)(wbase + ks * 32));
  }

  // ---- theta-phase identity: thread = (b_local = tid>>6, i_local = tid&63) ----
  const int bl = tid >> 6;         // 0..7
  const int ilc = tid & 63;        // 0..63
  const int i  = rg * 64 + ilc;    // my hidden unit
  const int b  = bg * 8 + bl;      // my batch
  float th = 0.f, s_own = 0.f, c_own = 1.f;

  // ---- init parity-0 state: paired-lane packed uint stores ----
  {
    if ((ilc & 1) == 0)
      st32((uint*)(scT + ((size_t)(0 * 4 + bg) * 16 + bl) * 1024 + i), 0x00000000u);       // sin = 0,0
    else
      st32((uint*)(scT + ((size_t)(0 * 4 + bg) * 16 + bl + 8) * 1024 + (i - 1)), 0x3C003C00u); // cos = 1,1
  }

  // prefetch inp for t=0 so it drains under the first barrier
  float inpv = inp[(size_t)b * NH + i];

  unsigned step = 1;
  gbar(flags, step, tid, rg, bg); ++step;

  for (int t = 0; t < T; ++t) {
    const int p = t & 1;

    // ---- B-fragments: my batch-group's 16 state rows only (32 KB/block) ----
    uint4 bf[16];
    ldB(scT + ((size_t)(p * 4 + bg) * 16 + m) * 1024 + kh * 512 + quad * 8, bf);

    // ---- MFMA: two independent 8-chains, then add ----
    f32x4 D0 = {0.f, 0.f, 0.f, 0.f}, D1 = {0.f, 0.f, 0.f, 0.f};
#pragma unroll
    for (int ks = 0; ks < 8; ++ks)
      D0 = __builtin_amdgcn_mfma_f32_16x16x32_f16(af[ks], __builtin_bit_cast(half8, bf[ks]), D0, 0, 0, 0);
#pragma unroll
    for (int ks = 8; ks < 16; ++ks)
      D1 = __builtin_amdgcn_mfma_f32_16x16x32_f16(af[ks], __builtin_bit_cast(half8, bf[ks]), D1, 0, 0, 0);
    const f32x4 D = D0 + D1;

    // lane holds D rows quad*4..+3 (M) of column m (N) -> pd[kh][rt][m][quad*4..]
    *(f32x4*)&pd[(((kh * 4 + rt) * 16) + m) * 20 + quad * 4] = D;
    __syncthreads();

    // ---- theta update for (i, b) ----
    const int rti = ilc >> 4, r16 = ilc & 15;
    const float S = pd[((0 + rti) * 16 + bl) * 20 + r16] + pd[((4 + rti) * 16 + bl) * 20 + r16];
    const float C = pd[((0 + rti) * 16 + bl + 8) * 20 + r16] + pd[((4 + rti) * 16 + bl + 8) * 20 + r16];
    const float coup = s_own * C - c_own * S;   // sin*ΣWcos - cos*ΣWsin
    th = fmodf(coup + inpv + th, TWO_PI_F);
    if (th < 0.f) th += TWO_PI_F;
    float s, c;
    sincosf(th, &s, &c);
    s_own = s; c_own = c;

    if (t == T - 1) break;

    // ---- prefetch next timestep's inp: HBM latency drains under the barrier,
    // off the post-barrier critical path (it used to share the ldB vmcnt(0)
    // window right after the barrier) ----
    inpv = inp[((size_t)(t + 1) * BATCH + b) * NH + i];

    // ---- publish fp16 state, paired lanes -> one uint store each ----
    const uint hs = __builtin_bit_cast(ushort, (_Float16)s);
    const uint hc = __builtin_bit_cast(ushort, (_Float16)c);
    const uint phs = (uint)__shfl_xor((int)hs, 1, 64);
    const uint phc = (uint)__shfl_xor((int)hc, 1, 64);
    const size_t dbase = (size_t)((p ^ 1) * 4 + bg) * 16;
    if ((ilc & 1) == 0)
      st32((uint*)(scT + (dbase + bl) * 1024 + i), hs | (phs << 16));
    else
      st32((uint*)(scT + (dbase + bl + 8) * 1024 + (i - 1)), phc | (hc << 16));

    gbar(flags, step, tid, rg, bg); ++step;
  }

  stF[(size_t)b * NH + i] = th;
}

// ---- readout ----
__global__ void readout(const float* __restrict__ stF,
                        const float* __restrict__ Wout,   // [10][1024]
                        const float* __restrict__ bout,   // [10]
                        float* __restrict__ out)          // [32][10]
{
  const int bb = blockIdx.x;
  const int lane = threadIdx.x;   // 64 threads
  float st[16];
#pragma unroll
  for (int u = 0; u < 16; ++u) st[u] = stF[(size_t)bb * NH + u * 64 + lane];
  for (int o = 0; o < NOUT; ++o) {
    float acc = 0.f;
#pragma unroll
    for (int u = 0; u < 16; ++u) acc += st[u] * Wout[o * NH + u * 64 + lane];
#pragma unroll
    for (int sh = 1; sh < 64; sh <<= 1) acc += __shfl_xor(acc, sh, 64);
    if (lane == 0) out[bb * NOUT + o] = acc + bout[o];
  }
}

extern "C" void kernel_launch(void* const* d_in, const int* in_sizes, int n_in,
                              void* d_out, int out_size, void* d_ws, size_t ws_size,
                              hipStream_t stream) {
  const float* x     = (const float*)d_in[0];
  const float* Wi_w  = (const float*)d_in[1];
  const float* Wi_b  = (const float*)d_in[2];
  const float* Wh    = (const float*)d_in[3];
  const float* omega = (const float*)d_in[4];
  const float* W_out = (const float*)d_in[5];
  const float* b_out = (const float*)d_in[6];

  char* ws = (char*)d_ws;
  ushort*   w16 = (ushort*)(ws + OFF_W16);
  float*    inp = (float*)(ws + OFF_INP);
  ushort*   scT = (ushort*)(ws + OFF_SCT);
  float*    stF = (float*)(ws + OFF_STF);
  unsigned* flg = (unsigned*)(ws + OFF_FLG);

  hipMemsetAsync(ws + OFF_FLG, 0, 8192, stream);

  prep_w16<<<dim3(NH * NH / 256), dim3(256), 0, stream>>>(Wh, w16);
  prep_inp<<<dim3(T, BATCH), dim3(256), 0, stream>>>(x, Wi_w, Wi_b, omega, inp);

  void* args[] = { (void*)&inp, (void*)&w16, (void*)&scT, (void*)&stF, (void*)&flg };
  hipError_t err = hipLaunchCooperativeKernel((const void*)kuramoto_scan,
                                              dim3(NBLK), dim3(NTHR), args, 0, stream);
  if (err != hipSuccess) {
    // 64 blocks at <=2 blocks/CU are trivially co-resident; normal launch is safe.
    (void)hipGetLastError();
    kuramoto_scan<<<dim3(NBLK), dim3(NTHR), 0, stream>>>(inp, w16, scT, stF, flg);
  }

  readout<<<dim3(BATCH), dim3(64), 0, stream>>>(stF, W_out, b_out, (float*)d_out);
}